// Round 8
// baseline (100.894 us; speedup 1.0000x reference)
//
#include <hip/hip_runtime.h>

// Problem constants (B, L, H, D, T) = (8, 4096, 8, 128, 128)
constexpr int B = 8;
constexpr int L = 4096;
constexpr int H = 8;
constexpr int D = 128;
constexpr int T = 128;

constexpr long long KV_ELEMS = (long long)B * L * H * D;  // floats per tensor
constexpr int TOTAL4 = (int)(KV_ELEMS / 4);               // 8,388,608 float4 per tensor

constexpr int NBLOCKS = 2048;
constexpr int NTHREADS = 256;
constexpr int STRIDE = NBLOCKS * NTHREADS;                // 524288 float4 = 8 MiB phase

// native clang vector type — __builtin_nontemporal_* requires this
typedef float f4 __attribute__((ext_vector_type(4)));

// ---------------------------------------------------------------------------
// Pure streaming copy: the absolute minimal 1R+1W loop. Launched once for K,
// once for V — kernel boundaries hard-serialize the two copies, so chip-wide
// there are exactly 2 address streams at any instant (no drift, no predicate
// in the load->store chain). Non-temporal: single-use data, skip LLC alloc.
// ---------------------------------------------------------------------------
__global__ __launch_bounds__(256) void kv_copy_nt(
    const f4* __restrict__ src,
    f4* __restrict__ dst)
{
    int i = blockIdx.x * NTHREADS + (int)threadIdx.x;
    // TOTAL4 / STRIDE == 16 exactly
    #pragma unroll 1
    for (int it = 0; it < 16; ++it, i += STRIDE) {
        __builtin_nontemporal_store(__builtin_nontemporal_load(&src[i]), &dst[i]);
    }
}

// ---------------------------------------------------------------------------
// Patch the <= B*T updated rows + write lengths. One block per (b,t)
// candidate row; uniform skip when t >= new_lengths[b]. <= 8 MB traffic.
// ---------------------------------------------------------------------------
__global__ __launch_bounds__(256) void kv_patch(
    const f4* __restrict__ new_keys,
    const f4* __restrict__ new_values,
    const int* __restrict__ lengths,
    const int* __restrict__ new_lengths,
    f4* __restrict__ out_k,
    f4* __restrict__ out_v,
    float* __restrict__ out_len)
{
    const int b = blockIdx.x >> 7;     // / T
    const int t = blockIdx.x & (T - 1);

    if (t < new_lengths[b]) {
        const int l = lengths[b];      // l in [0,2048), t < 128 -> l+t < L
        const int c = threadIdx.x;     // 256 threads == 256 float4 per row
        const int srci = ((b * T + t) << 8) + c;
        const int dsti = ((b * L + l + t) << 8) + c;
        out_k[dsti] = new_keys[srci];
        out_v[dsti] = new_values[srci];
    }

    if (blockIdx.x == 0 && threadIdx.x < B) {
        const int bb = threadIdx.x;
        out_len[bb] = (float)(lengths[bb] + new_lengths[bb]);
    }
}

extern "C" void kernel_launch(void* const* d_in, const int* in_sizes, int n_in,
                              void* d_out, int out_size, void* d_ws, size_t ws_size,
                              hipStream_t stream)
{
    const f4* keys        = (const f4*)d_in[0];
    const f4* values      = (const f4*)d_in[1];
    const int* lengths    = (const int*)d_in[2];
    const f4* new_keys    = (const f4*)d_in[3];
    const f4* new_values  = (const f4*)d_in[4];
    const int* new_lengths= (const int*)d_in[5];

    float* out     = (float*)d_out;
    f4* out_k      = (f4*)out;
    f4* out_v      = (f4*)(out + KV_ELEMS);
    float* out_len = out + 2 * KV_ELEMS;

    // 1) K copy, 2) V copy — hard-serialized pure 2-stream copies
    kv_copy_nt<<<NBLOCKS, NTHREADS, 0, stream>>>(keys,   out_k);
    kv_copy_nt<<<NBLOCKS, NTHREADS, 0, stream>>>(values, out_v);

    // 3) overwrite updated rows + lengths (same stream -> ordered)
    kv_patch<<<B * T, NTHREADS, 0, stream>>>(new_keys, new_values,
                                             lengths, new_lengths,
                                             out_k, out_v, out_len);
}

// Round 9
// 95.254 us; speedup vs baseline: 1.0592x; 1.0592x over previous
//
#include <hip/hip_runtime.h>

// Problem constants (B, L, H, D, T) = (8, 4096, 8, 128, 128)
constexpr int B = 8;
constexpr int L = 4096;
constexpr int H = 8;
constexpr int D = 128;
constexpr int T = 128;

constexpr long long KV_ELEMS = (long long)B * L * H * D;  // floats per tensor
constexpr int TOTAL4 = (int)(KV_ELEMS / 4);               // 8,388,608 float4 per tensor

constexpr int NBLOCKS  = 2048;
constexpr int NTHREADS = 256;
// Each block covers 512 consecutive float4 (8 KiB) per iteration: two
// fully-coalesced 1-KiB-per-wave loads at adjacent offsets -> 2x per-wave MLP
// with zero page-locality cost.  Per-iteration chip window = 16 MiB.
constexpr int PER_ITER = NBLOCKS * 512;                   // 1,048,576 float4
constexpr int ITERS    = TOTAL4 / PER_ITER;               // 8 per tensor

// native clang vector type — __builtin_nontemporal_* requires this
typedef float f4 __attribute__((ext_vector_type(4)));

__global__ __launch_bounds__(256) void kv_fused_phased2(
    const f4* __restrict__ keys,
    const f4* __restrict__ values,
    const int* __restrict__ lengths,
    const f4* __restrict__ new_keys,
    const f4* __restrict__ new_values,
    const int* __restrict__ new_lengths,
    f4* __restrict__ out_k,
    f4* __restrict__ out_v,
    float* __restrict__ out_len)
{
    const int tid  = (int)threadIdx.x;
    const int bofs = blockIdx.x * 512 + tid;

    #pragma unroll 1
    for (int it = 0; it < 2 * ITERS; ++it) {
        const bool is_k = (it < ITERS);
        const f4* __restrict__ src  = is_k ? keys     : values;
        const f4* __restrict__ nsrc = is_k ? new_keys : new_values;
        f4* __restrict__ dst        = is_k ? out_k    : out_v;

        const int i0 = (it & (ITERS - 1)) * PER_ITER + bofs;
        const int i1 = i0 + 256;

        // two independent fully-coalesced non-temporal loads (2x MLP)
        f4 va = __builtin_nontemporal_load(&src[i0]);
        f4 vb = __builtin_nontemporal_load(&src[i1]);

        // patch-select for row of i0 (wave-uniform: row fixed per instruction)
        {
            const int row = i0 >> 8;
            const int b   = row >> 12;
            const int p   = row & (L - 1);
            const int l   = lengths[b];
            const int nl  = new_lengths[b];
            if (p >= l && p < l + nl) {
                va = nsrc[((b * T + (p - l)) << 8) + (i0 & 255)];
            }
        }
        // patch-select for row of i1
        {
            const int row = i1 >> 8;
            const int b   = row >> 12;
            const int p   = row & (L - 1);
            const int l   = lengths[b];
            const int nl  = new_lengths[b];
            if (p >= l && p < l + nl) {
                vb = nsrc[((b * T + (p - l)) << 8) + (i1 & 255)];
            }
        }

        __builtin_nontemporal_store(va, &dst[i0]);
        __builtin_nontemporal_store(vb, &dst[i1]);
    }

    if (blockIdx.x == 0 && threadIdx.x < B) {
        const int bb = threadIdx.x;
        out_len[bb] = (float)(lengths[bb] + new_lengths[bb]);
    }
}

extern "C" void kernel_launch(void* const* d_in, const int* in_sizes, int n_in,
                              void* d_out, int out_size, void* d_ws, size_t ws_size,
                              hipStream_t stream)
{
    const f4* keys        = (const f4*)d_in[0];
    const f4* values      = (const f4*)d_in[1];
    const int* lengths    = (const int*)d_in[2];
    const f4* new_keys    = (const f4*)d_in[3];
    const f4* new_values  = (const f4*)d_in[4];
    const int* new_lengths= (const int*)d_in[5];

    float* out     = (float*)d_out;
    f4* out_k      = (f4*)out;
    f4* out_v      = (f4*)(out + KV_ELEMS);
    float* out_len = out + 2 * KV_ELEMS;

    kv_fused_phased2<<<NBLOCKS, NTHREADS, 0, stream>>>(keys, values, lengths,
                                                       new_keys, new_values, new_lengths,
                                                       out_k, out_v, out_len);
}